// Round 11
// baseline (271.545 us; speedup 1.0000x reference)
//
#include <hip/hip_runtime.h>

// Problem: B=16, C=8, H=W=512, N=16384
// plane = H*W = 1<<18 floats (1 MiB); items per plane = N = 1<<14
// total items per set = 2,097,152 ; 4 gathers per item across the two sets.
//
// R10 geometry: XCD-partitioned (blockIdx.x & 7 -> XCD, each owns 16 planes).
// Within an XCD, 1024 waves step through 8 "steps"; per step the waves cover
// 32768 items x 2 sets: even waves take set0, odd waves take set1 of the SAME
// 64-item span. Instantaneous gather window = 2 planes (2 MiB) per XCD
// (~4 MiB with inter-block drift) -> resident in the XCD's private 4 MiB L2,
// cutting divergent-gather miss latency vs the R9 4-plane/8 MiB window.

typedef int int4v __attribute__((ext_vector_type(4)));

constexpr int kXcds         = 8;
constexpr int kPlanesPerXcd = 16;                        // 128 planes / 8 XCDs
constexpr int kItemsPerXcd  = kPlanesPerXcd << 14;       // 262144
constexpr int kBlocksPerXcd = 256;                       // 8 blocks/CU
constexpr int kBlocks       = kBlocksPerXcd * kXcds;     // 2048
constexpr int kWavesPerXcd  = kBlocksPerXcd * 4;         // 1024
constexpr int kItemsPerStep = (kWavesPerXcd / 2) * 64;   // 32768 = 2 planes
constexpr int kSteps        = kItemsPerXcd / kItemsPerStep; // 8

__device__ __forceinline__ double wave_reduce_sum(double x) {
#pragma unroll
    for (int o = 32; o > 0; o >>= 1) x += __shfl_down(x, o, 64);
    return x;
}

__global__ __launch_bounds__(256) void bd_partial_kernel(
        const float* __restrict__ pred,
        const int*   __restrict__ iv0,
        const int*   __restrict__ iv1,
        double*      __restrict__ partials) {
    const int xcd  = blockIdx.x & 7;
    const int wv   = (blockIdx.x >> 3) * 4 + (threadIdx.x >> 6); // 0..1023 in XCD
    const int lane = threadIdx.x & 63;
    const int set  = wv & 1;                    // even wave: set0, odd: set1
    const int slot = (wv >> 1) * 64 + lane;     // 0..32767 item-slot within step

    const int4v* q = reinterpret_cast<const int4v*>(set ? iv1 : iv0);

    int i = xcd * kItemsPerXcd + slot;
    // idx data is stream-once: nontemporal keeps it from evicting the
    // prediction plane window out of the XCD's L2.
    int4v a = __builtin_nontemporal_load(q + i);

    double acc = 0.0;
#pragma unroll
    for (int s = 0; s < kSteps; ++s) {
        const float* plane = pred + ((size_t)(i >> 14) << 18);

        const float birth = plane[(a.x << 9) + a.y];
        const float death = plane[(a.z << 9) + a.w];

        if (s + 1 < kSteps) {                   // prefetch next step's indices
            i += kItemsPerStep;
            a = __builtin_nontemporal_load(q + i);
        }

        const float d = birth - death;
        acc += (double)d * (double)d;
    }

    acc = wave_reduce_sum(acc);
    __shared__ double sm[4];
    const int wid = threadIdx.x >> 6;
    if (lane == 0) sm[wid] = acc;
    __syncthreads();
    if (threadIdx.x == 0) partials[blockIdx.x] = sm[0] + sm[1] + sm[2] + sm[3];
}

__global__ __launch_bounds__(256) void bd_final_kernel(
        const double* __restrict__ partials, int n, float* __restrict__ out) {
    double acc = 0.0;
    for (int i = threadIdx.x; i < n; i += 256) acc += partials[i];
    acc = wave_reduce_sum(acc);
    __shared__ double sm[4];
    const int lane = threadIdx.x & 63;
    const int wid  = threadIdx.x >> 6;
    if (lane == 0) sm[wid] = acc;
    __syncthreads();
    if (threadIdx.x == 0)
        out[0] = (float)((sm[0] + sm[1] + sm[2] + sm[3]) * (1.0 / 16.0)); // /B
}

extern "C" void kernel_launch(void* const* d_in, const int* in_sizes, int n_in,
                              void* d_out, int out_size, void* d_ws, size_t ws_size,
                              hipStream_t stream) {
    const float* pred = (const float*)d_in[0];
    const int*   iv0  = (const int*)d_in[1];
    const int*   iv1  = (const int*)d_in[2];
    float*  out      = (float*)d_out;
    double* partials = (double*)d_ws;   // 2048 doubles = 16 KiB scratch

    bd_partial_kernel<<<kBlocks, 256, 0, stream>>>(pred, iv0, iv1, partials);
    bd_final_kernel<<<1, 256, 0, stream>>>(partials, kBlocks, out);
}

// Round 13
// 262.062 us; speedup vs baseline: 1.0362x; 1.0362x over previous
//
#include <hip/hip_runtime.h>

// Problem: B=16, C=8, H=W=512, N=16384
// plane = H*W = 1<<18 floats (1 MiB); items per plane = N = 1<<14
// 2,097,152 items; 4 random 4B gathers per item (2 sets x birth/death).
//
// Model (R1/R4/R9/R11): time pinned ~93-118us across 4x traffic variation ->
// per-XCD L2 random-request throughput wall (~1.05M req/XCD @ ~4.7 req/cyc).
// R4->R9 showed feeding the pipe harder (+waves,+MLP) = -14%. This round:
// max MLP = 8 gathers in flight per thread (2 items x 4 points), R9 geometry.

typedef int int4v __attribute__((ext_vector_type(4)));

constexpr int kXcds          = 8;
constexpr int kPlanesPerXcd  = 16;                   // 128 planes / 8 XCDs
constexpr int kItemsPerXcd   = kPlanesPerXcd << 14;  // 262144
constexpr int kBlocksPerXcd  = 256;                  // 8 blocks/CU
constexpr int kBlocks        = kBlocksPerXcd * kXcds;      // 2048
constexpr int kThreadsPerXcd = kBlocksPerXcd * 256;        // 65536
constexpr int kItemsPerIter  = kThreadsPerXcd * 2;         // 131072 (2 items/thread)
constexpr int kIters         = kItemsPerXcd / kItemsPerIter; // 2

__device__ __forceinline__ double wave_reduce_sum(double x) {
#pragma unroll
    for (int o = 32; o > 0; o >>= 1) x += __shfl_down(x, o, 64);
    return x;
}

__global__ __launch_bounds__(256) void bd_partial_kernel(
        const float* __restrict__ pred,
        const int*   __restrict__ iv0,
        const int*   __restrict__ iv1,
        double*      __restrict__ partials) {
    const int xcd   = blockIdx.x & 7;
    const int tloc  = (blockIdx.x >> 3) * 256 + threadIdx.x;  // 0..65535 in XCD
    const int ibase = xcd * kItemsPerXcd;

    const int4v* q0 = reinterpret_cast<const int4v*>(iv0);
    const int4v* q1 = reinterpret_cast<const int4v*>(iv1);

    // Two coalesced item streams per thread: i and i+65536.
    int i0 = ibase + tloc;
    int4v a0 = __builtin_nontemporal_load(q0 + i0);
    int4v b0 = __builtin_nontemporal_load(q1 + i0);
    int4v a1 = __builtin_nontemporal_load(q0 + i0 + kThreadsPerXcd);
    int4v b1 = __builtin_nontemporal_load(q1 + i0 + kThreadsPerXcd);

    double acc = 0.0;
#pragma unroll
    for (int it = 0; it < kIters; ++it) {
        const float* p0 = pred + ((size_t)((i0)                  >> 14) << 18);
        const float* p1 = pred + ((size_t)((i0 + kThreadsPerXcd) >> 14) << 18);

        // 8 independent divergent gathers in flight
        const float v0 = p0[(a0.x << 9) + a0.y];
        const float v1 = p0[(a0.z << 9) + a0.w];
        const float v2 = p0[(b0.x << 9) + b0.y];
        const float v3 = p0[(b0.z << 9) + b0.w];
        const float v4 = p1[(a1.x << 9) + a1.y];
        const float v5 = p1[(a1.z << 9) + a1.w];
        const float v6 = p1[(b1.x << 9) + b1.y];
        const float v7 = p1[(b1.z << 9) + b1.w];

        if (it + 1 < kIters) {            // prefetch next iteration's indices
            i0 += kItemsPerIter;
            a0 = __builtin_nontemporal_load(q0 + i0);
            b0 = __builtin_nontemporal_load(q1 + i0);
            a1 = __builtin_nontemporal_load(q0 + i0 + kThreadsPerXcd);
            b1 = __builtin_nontemporal_load(q1 + i0 + kThreadsPerXcd);
        }

        const float d0 = v0 - v1, d1 = v2 - v3, d2 = v4 - v5, d3 = v6 - v7;
        acc += (double)d0 * (double)d0 + (double)d1 * (double)d1
             + (double)d2 * (double)d2 + (double)d3 * (double)d3;
    }

    acc = wave_reduce_sum(acc);
    __shared__ double sm[4];
    const int lane = threadIdx.x & 63;
    const int wid  = threadIdx.x >> 6;
    if (lane == 0) sm[wid] = acc;
    __syncthreads();
    if (threadIdx.x == 0) partials[blockIdx.x] = sm[0] + sm[1] + sm[2] + sm[3];
}

__global__ __launch_bounds__(256) void bd_final_kernel(
        const double* __restrict__ partials, int n, float* __restrict__ out) {
    double acc = 0.0;
    for (int i = threadIdx.x; i < n; i += 256) acc += partials[i];
    acc = wave_reduce_sum(acc);
    __shared__ double sm[4];
    const int lane = threadIdx.x & 63;
    const int wid  = threadIdx.x >> 6;
    if (lane == 0) sm[wid] = acc;
    __syncthreads();
    if (threadIdx.x == 0)
        out[0] = (float)((sm[0] + sm[1] + sm[2] + sm[3]) * (1.0 / 16.0)); // /B
}

extern "C" void kernel_launch(void* const* d_in, const int* in_sizes, int n_in,
                              void* d_out, int out_size, void* d_ws, size_t ws_size,
                              hipStream_t stream) {
    const float* pred = (const float*)d_in[0];
    const int*   iv0  = (const int*)d_in[1];
    const int*   iv1  = (const int*)d_in[2];
    float*  out      = (float*)d_out;
    double* partials = (double*)d_ws;   // 2048 doubles = 16 KiB scratch

    bd_partial_kernel<<<kBlocks, 256, 0, stream>>>(pred, iv0, iv1, partials);
    bd_final_kernel<<<1, 256, 0, stream>>>(partials, kBlocks, out);
}